// Round 13
// baseline (117.189 us; speedup 1.0000x reference)
//
#include <hip/hip_runtime.h>
#include <hip/hip_fp16.h>

#define IN_C 64
#define HID_C 64
#define LAT_C 32
#define NMAX 50000
#define EMAX 800000
#define SLOTS 48     // padded CSR row cap (multiple of 8); max realized in-degree ~35
#define NB 196       // coarse buckets: dst>>8 (256 dsts each)
#define CAP 5120     // bucket capacity; E[bucket]=4096 -> 16-sigma margin
#define EPB 1024     // edges per phase-1 block

// Static device scratch — independent of ws_size, graph-capture safe.
__device__ float    g_dinv[NMAX];
__device__ __half   g_hf[NMAX * HID_C];    // fp16 h; scaled in-place to h*dinv by k_build2
__device__ __half   g_gf[NMAX * LAT_C];    // fp16 g*dinv (written pre-scaled)
__device__ int      g_cnt[NMAX];           // per-dst degree, padded to multiple of 8
__device__ int      g_bcnt[NB];            // bucket cursors (phase-1 reservations)
__device__ uint2    g_bucket[(size_t)NB * CAP];  // {(d<<16)|s, f32bits(ew)}
__device__ unsigned g_edgep[NMAX * SLOTS];       // row-major: (src<<16)|fp16bits(ew); 0-padded

// ---------------- build ----------------

__global__ void k_zero_bcnt() {
    int i = threadIdx.x;
    if (i < NB) g_bcnt[i] = 0;
}

// Phase 1: blocks [0,Bf) bucket-scatter edges (ONE global atomic per block-bucket);
//          blocks [Bf,Bf+Bg) compute h = x @ W1 (fp16 out) — fused.
__global__ __launch_bounds__(256) void k_scatter1(const int* __restrict__ ei,
                                                  const float* __restrict__ ew, int E,
                                                  const float* __restrict__ x,
                                                  const float* __restrict__ W,
                                                  int n, int Bf) {
    __shared__ float sW[64 * 64];
    __shared__ float sX[4][4 * 72];
    __shared__ int hist[NB];
    __shared__ int base[NB];

    if ((int)blockIdx.x < Bf) {
        int t = threadIdx.x;
        for (int i = t; i < NB; i += 256) hist[i] = 0;
        __syncthreads();
        int e0 = blockIdx.x * EPB;
        int dv[4], sv[4], off[4];
        float wv[4];
#pragma unroll
        for (int i = 0; i < 4; ++i) {
            int e = e0 + t + i * 256;   // coalesced
            if (e < E) {
                dv[i] = ei[E + e];
                sv[i] = ei[e];
                wv[i] = ew[e];
                off[i] = atomicAdd(&hist[dv[i] >> 8], 1);   // LDS atomic
            } else dv[i] = -1;
        }
        __syncthreads();
        for (int i = t; i < NB; i += 256)
            base[i] = (hist[i] > 0) ? atomicAdd(&g_bcnt[i], hist[i]) : 0;
        __syncthreads();
#pragma unroll
        for (int i = 0; i < 4; ++i) {
            if (dv[i] >= 0) {
                int b = dv[i] >> 8;
                int pos = base[b] + off[i];
                if (pos < CAP) {
                    uint2 r;
                    r.x = ((unsigned)dv[i] << 16) | (unsigned)sv[i];
                    r.y = __float_as_uint(wv[i]);
                    g_bucket[(size_t)b * CAP + pos] = r;
                }
            }
        }
        return;
    }

    int bid = blockIdx.x - Bf;
    int t = threadIdx.x;
    int wave = t >> 6, lane = t & 63;
    int nodeBase = bid * 16 + wave * 4;

    {
        int w4 = lane * 4;
        int qq = w4 >> 6, kk = w4 & 63;
        int node = nodeBase + qq;
        float4 v = make_float4(0.f, 0.f, 0.f, 0.f);
        if (node < n) v = *(const float4*)&x[(size_t)node * 64 + kk];
        *(float4*)&sX[wave][qq * 72 + kk] = v;
    }
    for (int i = t * 4; i < 64 * 64; i += 256 * 4)
        *(float4*)&sW[i] = *(const float4*)&W[i];
    __syncthreads();

    int q = lane >> 4, r = lane & 15;
    float4 acc = make_float4(0.f, 0.f, 0.f, 0.f);
#pragma unroll
    for (int k4 = 0; k4 < 16; ++k4) {
        float4 xk = *(const float4*)&sX[wave][q * 72 + k4 * 4];
        float4 w0 = *(const float4*)&sW[(k4 * 4 + 0) * 64 + r * 4];
        float4 w1 = *(const float4*)&sW[(k4 * 4 + 1) * 64 + r * 4];
        float4 w2 = *(const float4*)&sW[(k4 * 4 + 2) * 64 + r * 4];
        float4 w3 = *(const float4*)&sW[(k4 * 4 + 3) * 64 + r * 4];
        acc.x += xk.x * w0.x; acc.y += xk.x * w0.y; acc.z += xk.x * w0.z; acc.w += xk.x * w0.w;
        acc.x += xk.y * w1.x; acc.y += xk.y * w1.y; acc.z += xk.y * w1.z; acc.w += xk.y * w1.w;
        acc.x += xk.z * w2.x; acc.y += xk.z * w2.y; acc.z += xk.z * w2.z; acc.w += xk.z * w2.w;
        acc.x += xk.w * w3.x; acc.y += xk.w * w3.y; acc.z += xk.w * w3.z; acc.w += xk.w * w3.w;
    }
    int node = nodeBase + q;
    if (node < n) {
        ushort4 hv;
        hv.x = __half_as_ushort(__float2half_rn(acc.x));
        hv.y = __half_as_ushort(__float2half_rn(acc.y));
        hv.z = __half_as_ushort(__float2half_rn(acc.z));
        hv.w = __half_as_ushort(__float2half_rn(acc.w));
        *(ushort4*)&g_hf[(size_t)node * 64 + r * 4] = hv;
    }
}

// Phase 2: one block per bucket; local CSR via LDS atomics; rows 0-padded to a
// multiple of 8. Computes g_cnt + g_dinv, then scales its 256 h-rows in place by
// dinv (folds dinv[src] into the feature — gathers need NO per-edge dinv load).
__global__ __launch_bounds__(256) void k_build2(int n) {
    __shared__ int   cntl[256];
    __shared__ float degl[256];
    __shared__ float dinvl[256];
    int t = threadIdx.x;
    cntl[t] = 0;
    degl[t] = 0.f;
    __syncthreads();
    int b = blockIdx.x;
    int m = min(g_bcnt[b], CAP);
    const uint2* buck = &g_bucket[(size_t)b * CAP];
    for (int i = t; i < m; i += 256) {
        uint2 r = buck[i];
        int d = r.x >> 16;
        int dloc = d & 255;
        float w = __uint_as_float(r.y);
        int slot = atomicAdd(&cntl[dloc], 1);
        atomicAdd(&degl[dloc], w);
        if (slot < SLOTS) {
            unsigned rec = ((r.x & 0xffffu) << 16) |
                           (unsigned)__half_as_ushort(__float2half_rn(w));
            g_edgep[(size_t)d * SLOTS + slot] = rec;
        }
    }
    __syncthreads();
    int d = (b << 8) + t;
    if (d < n) {
        int c = min(cntl[t], SLOTS);
        int cp = min((c + 7) & ~7, SLOTS);
        for (int s = c; s < cp; ++s) g_edgep[(size_t)d * SLOTS + s] = 0;
        g_cnt[d] = cp;
        float di = rsqrtf(1.0f + degl[t]);
        g_dinv[d] = di;
        dinvl[t] = di;
    }
    __syncthreads();
    // scale h rows of this bucket's 256 dsts: g_hf[d] *= dinv[d]
    int rowsBase = b << 8;
    for (int i = t; i < 256 * 32; i += 256) {
        int r = i >> 5, el = i & 31;
        int d2 = rowsBase + r;
        if (d2 < n) {
            __half2* p = (__half2*)&g_hf[(size_t)d2 * 64] + el;
            float2 v = __half22float2(*p);
            float sc = dinvl[r];
            *p = __floats2half2_rn(v.x * sc, v.y * sc);
        }
    }
}

// ---------------- fused layer-1 aggregate + layer-2 transform ----------------
// One wave per node. lane=(half,u): channels {2u,2u+1} as __half2; halves split
// edge parity. Unroll-8 -> 4 independent row streams per half (MLP). Rows are
// pre-scaled by dinv[src]: acc = h_s[w] + sum ew*h_s[src]; agg = acc*dinv[w].
__global__ __launch_bounds__(256) void k_gather_fuse(const float* __restrict__ b1,
                                                     const float* __restrict__ W2, int n) {
    __shared__ float sW[64 * 32];
    __shared__ float sB[64];
    int t = threadIdx.x;
    for (int i = t * 4; i < 64 * 32; i += 256 * 4)
        *(float4*)&sW[i] = *(const float4*)&W2[i];
    if (t < 64) sB[t] = b1[t];
    __syncthreads();

    int w = (blockIdx.x * 256 + t) >> 6;
    int lane = t & 63;
    int half = lane >> 5;
    int u = lane & 31;                 // channel pair: 2u, 2u+1
    float2 accA = make_float2(0.f, 0.f), accB = make_float2(0.f, 0.f);
    float2 accC = make_float2(0.f, 0.f), accD = make_float2(0.f, 0.f);
    float dd = 0.f;
    if (w < n) {
        int len = g_cnt[w];            // multiple of 8
        dd = g_dinv[w];
        {   // self-loop: h_scaled[w] (x dd at the end -> dd^2 * h[w])
            float2 sv = __half22float2(*(const __half2*)&g_hf[(size_t)w * 64 + 2 * u]);
            float hs = half ? 0.f : 1.f;
            accA.x = sv.x * hs; accA.y = sv.y * hs;
        }
        const unsigned* row = &g_edgep[(size_t)w * SLOTS];
        for (int j = 0; j < len; j += 8) {
            uint4 ra = *(const uint4*)&row[j];
            uint4 rb = *(const uint4*)&row[j + 4];
            unsigned eA = half ? ra.y : ra.x;
            unsigned eB = half ? ra.w : ra.z;
            unsigned eC = half ? rb.y : rb.x;
            unsigned eD = half ? rb.w : rb.z;
            float nA = __half2float(__ushort_as_half((unsigned short)(eA & 0xffffu)));
            float nB = __half2float(__ushort_as_half((unsigned short)(eB & 0xffffu)));
            float nC = __half2float(__ushort_as_half((unsigned short)(eC & 0xffffu)));
            float nD = __half2float(__ushort_as_half((unsigned short)(eD & 0xffffu)));
            float2 fA = __half22float2(*(const __half2*)&g_hf[(size_t)(eA >> 16) * 64 + 2 * u]);
            float2 fB = __half22float2(*(const __half2*)&g_hf[(size_t)(eB >> 16) * 64 + 2 * u]);
            float2 fC = __half22float2(*(const __half2*)&g_hf[(size_t)(eC >> 16) * 64 + 2 * u]);
            float2 fD = __half22float2(*(const __half2*)&g_hf[(size_t)(eD >> 16) * 64 + 2 * u]);
            accA.x += fA.x * nA; accA.y += fA.y * nA;
            accB.x += fB.x * nB; accB.y += fB.y * nB;
            accC.x += fC.x * nC; accC.y += fC.y * nC;
            accD.x += fD.x * nD; accD.y += fD.y * nD;
        }
    }
    float ax = (accA.x + accB.x) + (accC.x + accD.x);
    float ay = (accA.y + accB.y) + (accC.y + accD.y);
    ax += __shfl_xor(ax, 32, 64);
    ay += __shfl_xor(ay, 32, 64);
    float2 a2 = make_float2(0.f, 0.f);
    if (w < n) {
        a2.x = fmaxf(ax * dd + sB[2 * u], 0.f);
        a2.y = fmaxf(ay * dd + sB[2 * u + 1], 0.f);
    }

    // Phase B: gsum[c] over k; half h covers k = 32h..32h+31 (pairs in lanes 16h..16h+15).
    int c = u;
    float gsum = 0.f;
#pragma unroll
    for (int i = 0; i < 16; ++i) {
        int srcl = (half << 4) + i;            // lane holding pair k=2*srcl
        float px = __shfl(a2.x, srcl, 64);
        float py = __shfl(a2.y, srcl, 64);
        gsum += px * sW[(2 * srcl) * 32 + c] + py * sW[(2 * srcl + 1) * 32 + c];
    }
    gsum += __shfl_xor(gsum, 32, 64);
    float gscaled = gsum * dd;                 // store g*dinv (pre-scaled for layer 2)
    float gnext = __shfl_down(gscaled, 1, 64);
    if (w < n && half == 0 && (u & 1) == 0)
        *(__half2*)&g_gf[(size_t)w * 32 + u] = __floats2half2_rn(gscaled, gnext);
}

// ---------------- layer-2 aggregate ----------------
// Half-wave per node; quarter q = edge parity, u in [0,16): channels {2u,2u+1}.
// Unroll-8 -> 4 streams per quarter. g rows pre-scaled by dinv[src].
__global__ __launch_bounds__(256) void k_gather32(float* __restrict__ out,
                                                  const float* __restrict__ b2, int n) {
    int t = threadIdx.x;
    int hw = (blockIdx.x * 256 + t) >> 5;
    int lane = t & 31;
    int q = lane >> 4;
    int u = lane & 15;                 // channel pair: 2u, 2u+1
    if (hw >= n) return;
    int len = g_cnt[hw];               // multiple of 8
    float dd = g_dinv[hw];
    float2 accA = make_float2(0.f, 0.f), accB = make_float2(0.f, 0.f);
    float2 accC = make_float2(0.f, 0.f), accD = make_float2(0.f, 0.f);
    {   // self-loop: g_scaled[hw] (x dd at end -> dd^2 * g[hw])
        float2 sv = __half22float2(*(const __half2*)&g_gf[(size_t)hw * 32 + 2 * u]);
        float hs = q ? 0.f : 1.f;
        accA.x = sv.x * hs; accA.y = sv.y * hs;
    }
    const unsigned* row = &g_edgep[(size_t)hw * SLOTS];
    for (int j = 0; j < len; j += 8) {
        uint4 ra = *(const uint4*)&row[j];
        uint4 rb = *(const uint4*)&row[j + 4];
        unsigned eA = q ? ra.y : ra.x;
        unsigned eB = q ? ra.w : ra.z;
        unsigned eC = q ? rb.y : rb.x;
        unsigned eD = q ? rb.w : rb.z;
        float nA = __half2float(__ushort_as_half((unsigned short)(eA & 0xffffu)));
        float nB = __half2float(__ushort_as_half((unsigned short)(eB & 0xffffu)));
        float nC = __half2float(__ushort_as_half((unsigned short)(eC & 0xffffu)));
        float nD = __half2float(__ushort_as_half((unsigned short)(eD & 0xffffu)));
        float2 fA = __half22float2(*(const __half2*)&g_gf[(size_t)(eA >> 16) * 32 + 2 * u]);
        float2 fB = __half22float2(*(const __half2*)&g_gf[(size_t)(eB >> 16) * 32 + 2 * u]);
        float2 fC = __half22float2(*(const __half2*)&g_gf[(size_t)(eC >> 16) * 32 + 2 * u]);
        float2 fD = __half22float2(*(const __half2*)&g_gf[(size_t)(eD >> 16) * 32 + 2 * u]);
        accA.x += fA.x * nA; accA.y += fA.y * nA;
        accB.x += fB.x * nB; accB.y += fB.y * nB;
        accC.x += fC.x * nC; accC.y += fC.y * nC;
        accD.x += fD.x * nD; accD.y += fD.y * nD;
    }
    float ax = (accA.x + accB.x) + (accC.x + accD.x);
    float ay = (accA.y + accB.y) + (accC.y + accD.y);
    ax += __shfl_xor(ax, 16, 64);
    ay += __shfl_xor(ay, 16, 64);
    if (q == 0) {
        float2 o;
        o.x = fmaxf(ax * dd + b2[2 * u], 0.f);
        o.y = fmaxf(ay * dd + b2[2 * u + 1], 0.f);
        *(float2*)&out[(size_t)hw * 32 + 2 * u] = o;
    }
}

// ---------------- launch ----------------

extern "C" void kernel_launch(void* const* d_in, const int* in_sizes, int n_in,
                              void* d_out, int out_size, void* d_ws, size_t ws_size,
                              hipStream_t stream) {
    const float* x  = (const float*)d_in[0];
    const int*   ei = (const int*)d_in[1];     // int32 [2][E]
    const float* ew = (const float*)d_in[2];
    const float* W1 = (const float*)d_in[3];
    const float* b1 = (const float*)d_in[4];
    const float* W2 = (const float*)d_in[5];
    const float* b2 = (const float*)d_in[6];
    float* out = (float*)d_out;

    int n = in_sizes[0] / IN_C;   // 50000
    if (n > NMAX) n = NMAX;
    int E = in_sizes[2];          // 800000
    if (E > EMAX) E = EMAX;

    int Bf = (E + EPB - 1) / EPB;   // phase-1 scatter blocks (~782)
    int Bg = (n + 15) / 16;         // gemm64 blocks

    // 1) zero bucket cursors
    k_zero_bcnt<<<1, 256, 0, stream>>>();

    // 2) phase 1: bucket-scatter edges  ||  h = x @ W1 (fp16)
    k_scatter1<<<Bf + Bg, 256, 0, stream>>>(ei, ew, E, x, W1, n, Bf);

    // 3) phase 2: per-bucket CSR + g_cnt + g_dinv + in-place h *= dinv
    k_build2<<<NB, 256, 0, stream>>>(n);

    // 4) fused: agg = gather(h_scaled)*dinv; g_scaled = relu(agg+b1)@W2 * dinv
    k_gather_fuse<<<(n * 64 + 255) / 256, 256, 0, stream>>>(b1, W2, n);

    // 5) out = relu(gather(g_scaled)*dinv + b2)
    k_gather32<<<(n * 32 + 255) / 256, 256, 0, stream>>>(out, b2, n);
}